// Round 17
// baseline (360.337 us; speedup 1.0000x reference)
//
#include <hip/hip_runtime.h>
#include <hip/hip_bf16.h>
#include <math.h>

typedef __attribute__((ext_vector_type(8))) short short8;
typedef __attribute__((ext_vector_type(4))) float floatx4;

__device__ __forceinline__ float bf2f(unsigned short u) {
  union { unsigned int i; float f; } x; x.i = ((unsigned int)u) << 16; return x.f;
}
__device__ __forceinline__ unsigned short f2bf(float f) {
  union { float f; unsigned int i; } x; x.f = f;
  unsigned int r = x.i + 0x7FFFu + ((x.i >> 16) & 1u);
  return (unsigned short)(r >> 16);
}
__device__ __forceinline__ unsigned int pack2bf(float a, float b) {
  return (unsigned int)f2bf(a) | ((unsigned int)f2bf(b) << 16);
}
__device__ __forceinline__ void gl16(const void* g, void* l) {
  __builtin_amdgcn_global_load_lds(
      (const __attribute__((address_space(1))) unsigned int*)g,
      (__attribute__((address_space(3))) unsigned int*)l, 16, 0, 0);
}

// ---------------- fused fp32 -> bf16 cast (all 5 tensors, one launch) ----------------
__global__ void cvt_all(const float* __restrict__ x,  const float* __restrict__ wq,
                        const float* __restrict__ wk, const float* __restrict__ wv,
                        const float* __restrict__ wo,
                        unsigned short* __restrict__ xb,
                        unsigned short* __restrict__ qkvw,
                        unsigned short* __restrict__ wob) {
  int i = blockIdx.x * blockDim.x + threadIdx.x;     // float4 index, < 6815744
  const float* src; unsigned short* dst; int off;
  if (i < 4194304)      { src = x;  dst = xb;             off = i; }
  else if (i < 5242880) { src = wq; dst = qkvw;           off = i - 4194304; }
  else if (i < 5505024) { src = wk; dst = qkvw + 4194304; off = i - 5242880; }
  else if (i < 5767168) { src = wv; dst = qkvw + 5242880; off = i - 5505024; }
  else                  { src = wo; dst = wob;            off = i - 5767168; }
  float4 v = ((const float4*)src)[off];
  ushort4 o;
  o.x = f2bf(v.x); o.y = f2bf(v.y); o.z = f2bf(v.z); o.w = f2bf(v.w);
  ((ushort4*)dst)[off] = o;
}

// ---------------- GEMM: C = A(MxK) * Bw(NxK)^T (r11/r15/r16-verified structure) ----------------
// v5 K-loop: 256x256 tile, BK=64, 8 waves (2Mx4N), 128 KB dynamic LDS,
// in-wave software pipeline, one barrier + one counted drain per K-tile.
// MODE 1: fused QKV + RoPE in Q/K epilogue. NEW (r17): Q scale folds log2(e)
// (log2-domain softmax downstream -- the only change vs r16 is the constant).
// MODE 0: f32 row-major out (ld=N).
template<int MODE>
__global__ __launch_bounds__(512, 2) void gemm_bt(const unsigned short* __restrict__ A,
                                                  const unsigned short* __restrict__ Bw,
                                                  void* __restrict__ out0,
                                                  unsigned short* __restrict__ vtg,
                                                  const float* __restrict__ cosf,
                                                  const float* __restrict__ sinf,
                                                  int M, int N, int K, int nbx) {
  extern __shared__ unsigned short SM[];   // 128 KB
  const int nb = gridDim.x;
  const int bid = blockIdx.x;
  const int tile = (bid & 7) * (nb >> 3) + (bid >> 3);   // 8 XCDs, nb % 8 == 0
  const int n0 = (tile % nbx) * 256, m0 = (tile / nbx) * 256;
  const int tid = threadIdx.x;
  const int lane = tid & 63, wave = tid >> 6;
  const int wm = wave >> 2, wn = wave & 3;               // 2M x 4N wave grid
  const int r = lane & 15, g = lane >> 4;
  const int rh = r >> 1;
  const int slot = (((r & 1) << 2) | g) ^ rh;            // read-side granule slot

  const int sg8 = (tid & 7) ^ ((tid >> 3) & 7);
  const int srow = 2 * (tid >> 3) + (sg8 >> 2);
  const int scol = (sg8 & 3) * 8;
  const unsigned short* Agb = A  + (size_t)(m0 + srow) * K + scol;
  const unsigned short* Bgb = Bw + (size_t)(n0 + srow) * K + scol;
  const size_t K128 = (size_t)K * 128;
  char* const SMb = (char*)SM;

  const int aob = (wm * 64 + rh) * 64 + slot * 8;         // + kh*8192 + i*512
  const int bob = 16384 + (wn * 32 + rh) * 64 + slot * 8; // + kh*8192 + j*512

  auto STA = [&](int s, int t, int kh) {
    const unsigned short* gp = Agb + ((size_t)t << 6) + kh * 32;
    char* d = SMb + s * 65536 + kh * 16384 + wave * 1024;
    gl16(gp,        d);
    gl16(gp + K128, d + 8192);
  };
  auto STB = [&](int s, int t, int kh) {
    const unsigned short* gp = Bgb + ((size_t)t << 6) + kh * 32;
    char* d = SMb + s * 65536 + 32768 + kh * 16384 + wave * 1024;
    gl16(gp,        d);
    gl16(gp + K128, d + 8192);
  };

  floatx4 acc[8][4] = {};
  const int NT = K >> 6;

  STA(0, 0, 0); STB(0, 0, 0);
  STA(0, 0, 1); STB(0, 0, 1);
  asm volatile("s_waitcnt vmcnt(0)" ::: "memory");
  __builtin_amdgcn_s_barrier();
  asm volatile("" ::: "memory");

  short8 bfrA[4], afA[4];
#pragma unroll
  for (int j = 0; j < 4; ++j) bfrA[j] = *(const short8*)&SM[bob + j * 512];
#pragma unroll
  for (int i = 0; i < 4; ++i) afA[i] = *(const short8*)&SM[aob + i * 512];

  for (int t = 0; t < NT; ++t) {
    const int s = t & 1;
    const unsigned short* Ls = SM + s * 32768;         // ushort units
    const unsigned short* Ln = SM + (s ^ 1) * 32768;
    const bool pf = (t + 1 < NT);
    short8 afB[4], bfrB[4], afA2[4], afB2[4];

    // ---- q0: MFMA(kh0, i0-3); read kh0 i4-7; stage t+1 kh0 ----
#pragma unroll
    for (int i = 0; i < 4; ++i) afB[i] = *(const short8*)&Ls[aob + (4 + i) * 512];
    if (pf) { STA(s ^ 1, t + 1, 0); STB(s ^ 1, t + 1, 0); }
    __builtin_amdgcn_s_setprio(1);
#pragma unroll
    for (int i = 0; i < 4; ++i)
#pragma unroll
      for (int j = 0; j < 4; ++j)
        acc[i][j] = __builtin_amdgcn_mfma_f32_16x16x32_bf16(afA[i], bfrA[j], acc[i][j], 0, 0, 0);
    __builtin_amdgcn_s_setprio(0);

    // ---- q1: MFMA(kh0, i4-7); read kh1 B + kh1 i0-3; stage t+1 kh1 ----
#pragma unroll
    for (int j = 0; j < 4; ++j) bfrB[j] = *(const short8*)&Ls[bob + 8192 + j * 512];
#pragma unroll
    for (int i = 0; i < 4; ++i) afA2[i] = *(const short8*)&Ls[aob + 8192 + i * 512];
    if (pf) { STA(s ^ 1, t + 1, 1); STB(s ^ 1, t + 1, 1); }
    __builtin_amdgcn_s_setprio(1);
#pragma unroll
    for (int i = 0; i < 4; ++i)
#pragma unroll
      for (int j = 0; j < 4; ++j)
        acc[4 + i][j] = __builtin_amdgcn_mfma_f32_16x16x32_bf16(afB[i], bfrA[j], acc[4 + i][j], 0, 0, 0);
    __builtin_amdgcn_s_setprio(0);

    // ---- q2: MFMA(kh1, i0-3); read kh1 i4-7 ----
#pragma unroll
    for (int i = 0; i < 4; ++i) afB2[i] = *(const short8*)&Ls[aob + 8192 + (4 + i) * 512];
    __builtin_amdgcn_s_setprio(1);
#pragma unroll
    for (int i = 0; i < 4; ++i)
#pragma unroll
      for (int j = 0; j < 4; ++j)
        acc[i][j] = __builtin_amdgcn_mfma_f32_16x16x32_bf16(afA2[i], bfrB[j], acc[i][j], 0, 0, 0);
    __builtin_amdgcn_s_setprio(0);

    // ---- q3: drain reads (WAR) + confirm stages (RAW); barrier; read-ahead ----
    asm volatile("s_waitcnt lgkmcnt(0)" ::: "memory");
    if (pf) asm volatile("s_waitcnt vmcnt(0)" ::: "memory");
    __builtin_amdgcn_s_barrier();
    asm volatile("" ::: "memory");
    if (pf) {
#pragma unroll
      for (int j = 0; j < 4; ++j) bfrA[j] = *(const short8*)&Ln[bob + j * 512];
#pragma unroll
      for (int i = 0; i < 4; ++i) afA[i] = *(const short8*)&Ln[aob + i * 512];
    }
    __builtin_amdgcn_s_setprio(1);
#pragma unroll
    for (int i = 0; i < 4; ++i)
#pragma unroll
      for (int j = 0; j < 4; ++j)
        acc[4 + i][j] = __builtin_amdgcn_mfma_f32_16x16x32_bf16(afB2[i], bfrB[j], acc[4 + i][j], 0, 0, 0);
    __builtin_amdgcn_s_setprio(0);
  }

  // ---- LDS-bounce epilogues ----
  if (MODE == 0) {
    float* SMf = (float*)SM;                 // slab: 256 rows x 64 f32 = 64 KB
    float* outp = (float*)out0;
#pragma unroll
    for (int sp = 0; sp < 4; ++sp) {
      __syncthreads();
      if (wn == sp) {
#pragma unroll
        for (int i = 0; i < 8; ++i)
#pragma unroll
          for (int j = 0; j < 4; ++j)
#pragma unroll
            for (int q = 0; q < 4; ++q)
              SMf[(wm * 128 + i * 16 + g * 4 + q) * 64 + j * 16 + r] = acc[i][j][q];
      }
      __syncthreads();
#pragma unroll
      for (int it = 0; it < 8; ++it) {
        int c = it * 512 + tid;
        int ml = c >> 4, c4 = c & 15;
        float4 v = *(float4*)&SMf[ml * 64 + c4 * 4];
        *(float4*)(outp + (size_t)(m0 + ml) * N + n0 + sp * 64 + c4 * 4) = v;
      }
    }
  } else if (n0 < 2560) {                    // Q/K region: bf16 row-major + fused RoPE
    unsigned short* outp = (unsigned short*)out0;
    // Q scale = log2(e)/sqrt(128): softmax runs in log2 domain downstream
    const float scale = (n0 < 2048) ? 0.12751744577367222f : 1.0f;
#pragma unroll
    for (int sp = 0; sp < 2; ++sp) {
      __syncthreads();
      if (wm == sp) {
#pragma unroll
        for (int i = 0; i < 8; ++i)
#pragma unroll
          for (int j = 0; j < 4; ++j)
#pragma unroll
            for (int q = 0; q < 4; ++q)
              SM[(i * 16 + g * 4 + q) * 256 + wn * 64 + j * 16 + r] = f2bf(acc[i][j][q]);
      }
      __syncthreads();
#pragma unroll
      for (int it = 0; it < 8; ++it) {
        int c = it * 512 + tid;
        int ml = c >> 5, c8 = c & 31;
        union { short8 s; unsigned short u[8]; } v;
        v.s = *(short8*)&SM[ml * 256 + c8 * 8];
        const int row = m0 + sp * 128 + ml;            // global token row
        const int tpos = row & 2047;
        const int d8 = ((n0 + c8 * 8) & 127) >> 3;     // pair-quad index within head
        float4 cc = *(const float4*)(cosf + (size_t)tpos * 64 + d8 * 4);
        float4 ss = *(const float4*)(sinf + (size_t)tpos * 64 + d8 * 4);
        float cv[4] = {cc.x, cc.y, cc.z, cc.w};
        float sv[4] = {ss.x, ss.y, ss.z, ss.w};
#pragma unroll
        for (int jj = 0; jj < 4; ++jj) {
          float tr = bf2f(v.u[2 * jj]);
          float ti = bf2f(v.u[2 * jj + 1]);
          float orr = (tr * cv[jj] - ti * sv[jj]) * scale;
          float oi  = (tr * sv[jj] + ti * cv[jj]) * scale;
          v.u[2 * jj]     = f2bf(orr);
          v.u[2 * jj + 1] = f2bf(oi);
        }
        *(short8*)(outp + (size_t)row * N + n0 + c8 * 8) = v.s;
      }
    }
  } else {                                   // V region: bf16 transposed, ld=8192 (no RoPE)
#pragma unroll
    for (int sp = 0; sp < 8; ++sp) {
      __syncthreads();
      if (wave == sp) {
#pragma unroll
        for (int i = 0; i < 8; ++i)
#pragma unroll
          for (int j = 0; j < 4; ++j)
#pragma unroll
            for (int q = 0; q < 4; ++q) {
              int ml = i * 16 + g * 4 + q;            // 0..127 (wave's m range)
              int nl = j * 16 + r;                    // 0..63  (wave's n range)
              SM[nl * 128 + (((ml >> 3) ^ (nl & 7)) << 3) + (ml & 7)] = f2bf(acc[i][j][q]);
            }
      }
      __syncthreads();
#pragma unroll
      for (int it = 0; it < 2; ++it) {
        int c = it * 512 + tid;
        int nl = c >> 4, m8 = c & 15;
        short8 v = *(short8*)&SM[nl * 128 + ((m8 ^ (nl & 7)) << 3)];
        *(short8*)(vtg + (size_t)(n0 - 2560 + (sp & 3) * 64 + nl) * 8192 + m0 + (sp >> 2) * 128 + m8 * 8) = v;
      }
    }
  }
}

// ---------------- causal GQA flash attention ----------------
// r7/r16 body; NEW (r17): softmax in LOG2 DOMAIN -- log2(e) folded into Q at
// the fused RoPE, exps are builtin exp2f (v_exp_f32 computes 2^x natively,
// deleting __expf's x*log2e mul), defer-max threshold 8*log2e = 11.5416.
// No inline-asm changes (r6's failed variant used hand-asm for both cvt_pk
// and exp2; this isolates the log2 math on the safe instruction path).
__global__ __launch_bounds__(256, 2) void attn_fwd(const unsigned short* __restrict__ QKV,
                                                   const unsigned short* __restrict__ VT,
                                                   unsigned short* __restrict__ O) {
  constexpr int T = 2048;
  constexpr int LDQ = 3072;
  constexpr float NEG = -1e30f;
  __shared__ unsigned short Ks[2][64 * 128];
  __shared__ unsigned short Vs[2][128 * 64];
  const int gid = blockIdx.x;
  const int hb  = gid & 63;                // h + 16*b
  const int qb  = 15 - (gid >> 6);         // 15..0 -- biggest q-block first
  const int h = hb & 15, b = hb >> 4;
  const int kvh = h >> 2;
  const int tid = threadIdx.x, lane = tid & 63, w = tid >> 6;
  const int r = lane & 15, g = lane >> 4;
  const int rbase = (r & 3) + ((r >> 2) << 3);
  const int swzr  = (r & 3) | (((r >> 2) & 1) << 2);
  const size_t bT = (size_t)b * T;

  const unsigned short* Kgb = QKV + bT * LDQ + 2048 + kvh * 128;
  const unsigned short* Vgb = VT + (size_t)(kvh * 128) * 8192 + b * 2048;

  auto STAGE = [&](int bi, int kv0) {
#pragma unroll
    for (int t2 = 0; t2 < 4; ++t2) {
      int ck = w * 4 + t2;
      { int row = ck * 4 + (lane >> 4); int c16 = lane & 15;
        int swz = (row & 3) | (((row >> 3) & 1) << 2);
        gl16(Kgb + (size_t)(kv0 + row) * LDQ + ((c16 ^ swz) << 3),
             (char*)(&Ks[bi][0]) + ck * 1024); }
      { int row = ck * 8 + (lane >> 3); int c16 = lane & 7;
        gl16(Vgb + (size_t)row * 8192 + kv0 + ((c16 ^ (row & 7)) << 3),
             (char*)(&Vs[bi][0]) + ck * 1024); }
    }
  };

  const int q0 = qb * 128;

  short8 qf[2][4];
#pragma unroll
  for (int qt = 0; qt < 2; ++qt) {
    const unsigned short* qp = QKV + (bT + q0 + w * 32 + qt * 16 + r) * LDQ + h * 128;
#pragma unroll
    for (int c = 0; c < 4; ++c) qf[qt][c] = *(const short8*)(qp + c * 32 + g * 8);
  }

  floatx4 acc[8][2] = {};
  float mrun[2] = {NEG, NEG};
  float lrun[2] = {0.f, 0.f};

  const int ntiles = (q0 + 128) >> 6;
  STAGE(0, 0);
  asm volatile("s_waitcnt vmcnt(0)" ::: "memory");
  __syncthreads();

  for (int t = 0; t < ntiles; ++t) {
    const int cur = t & 1;
    const int kv0 = t << 6;
    if (t + 1 < ntiles) STAGE(cur ^ 1, (t + 1) << 6);

    if (kv0 <= q0 + w * 32 + 31) {
      floatx4 st[2][4] = {};
      __builtin_amdgcn_s_setprio(1);
#pragma unroll
      for (int c = 0; c < 4; ++c) {
        short8 kf[4];
#pragma unroll
        for (int kt = 0; kt < 4; ++kt) {
          const int row = rbase + ((kt & 1) << 2) + ((kt >> 1) << 5);
          kf[kt] = *(const short8*)&Ks[cur][row * 128 + (((g + 4 * c) ^ swzr) << 3)];
        }
#pragma unroll
        for (int qt = 0; qt < 2; ++qt)
#pragma unroll
          for (int kt = 0; kt < 4; ++kt)
            st[qt][kt] = __builtin_amdgcn_mfma_f32_16x16x32_bf16(kf[kt], qf[qt][c], st[qt][kt], 0, 0, 0);
      }
      __builtin_amdgcn_s_setprio(0);

      short8 va[2][8];
#pragma unroll
      for (int kc = 0; kc < 2; ++kc)
#pragma unroll
        for (int dt = 0; dt < 8; ++dt)
          va[kc][dt] = *(const short8*)&Vs[cur][(dt * 16 + r) * 64 + (((g + 4 * kc) ^ (r & 7)) << 3)];

#pragma unroll
      for (int qt = 0; qt < 2; ++qt) {
        const int qmin = q0 + w * 32 + qt * 16;
        const int qrow = qmin + r;
        float x[4][4];
        bool needmask = (kv0 + 64 > qmin);
#pragma unroll
        for (int kt = 0; kt < 4; ++kt) {
          const int kvb = kv0 + ((kt >> 1) << 5) + (g << 3) + ((kt & 1) << 2);
#pragma unroll
          for (int j = 0; j < 4; ++j) {
            float v = st[qt][kt][j];
            if (needmask) v = (kvb + j <= qrow) ? v : NEG;
            x[kt][j] = v;
          }
        }
        float mloc = x[0][0];
#pragma unroll
        for (int kt = 0; kt < 4; ++kt)
#pragma unroll
          for (int j = 0; j < 4; ++j) mloc = fmaxf(mloc, x[kt][j]);
        mloc = fmaxf(mloc, __shfl_xor(mloc, 16));
        mloc = fmaxf(mloc, __shfl_xor(mloc, 32));
        if (!__all(mloc <= mrun[qt] + 11.5416f)) {   // defer-max (T13), log2 domain
          float mnew = fmaxf(mrun[qt], mloc);
          float al = exp2f(mrun[qt] - mnew);
          mrun[qt] = mnew;
          lrun[qt] *= al;
#pragma unroll
          for (int dt = 0; dt < 8; ++dt) acc[dt][qt] *= al;
        }
        float pr[4][4], ssum = 0.f;
#pragma unroll
        for (int kt = 0; kt < 4; ++kt)
#pragma unroll
          for (int j = 0; j < 4; ++j) { pr[kt][j] = exp2f(x[kt][j] - mrun[qt]); ssum += pr[kt][j]; }
        ssum += __shfl_xor(ssum, 16);
        ssum += __shfl_xor(ssum, 32);
        lrun[qt] += ssum;
        uint2 pk[4];
#pragma unroll
        for (int kt = 0; kt < 4; ++kt) {
          pk[kt].x = pack2bf(pr[kt][0], pr[kt][1]);
          pk[kt].y = pack2bf(pr[kt][2], pr[kt][3]);
        }
        __builtin_amdgcn_s_setprio(1);
#pragma unroll
        for (int kc = 0; kc < 2; ++kc) {
          union { unsigned int u[4]; short8 s; } bw;
          bw.u[0] = pk[2 * kc].x;
          bw.u[1] = pk[2 * kc].y;
          bw.u[2] = pk[2 * kc + 1].x;
          bw.u[3] = pk[2 * kc + 1].y;
#pragma unroll
          for (int dt = 0; dt < 8; ++dt)
            acc[dt][qt] = __builtin_amdgcn_mfma_f32_16x16x32_bf16(va[kc][dt], bw.s, acc[dt][qt], 0, 0, 0);
        }
        __builtin_amdgcn_s_setprio(0);
      }
    }

    asm volatile("s_waitcnt vmcnt(0)" ::: "memory");
    __syncthreads();
  }

  // ---- epilogue: O[q][d] = acc^T / l ----
#pragma unroll
  for (int qt = 0; qt < 2; ++qt) {
    float inv = 1.f / lrun[qt];
    unsigned short* op = O + (bT + q0 + w * 32 + qt * 16 + r) * 2048 + h * 128;
#pragma unroll
    for (int dt = 0; dt < 8; ++dt) {
      uint2 pkd;
      pkd.x = pack2bf(acc[dt][qt][0] * inv, acc[dt][qt][1] * inv);
      pkd.y = pack2bf(acc[dt][qt][2] * inv, acc[dt][qt][3] * inv);
      *(uint2*)(op + dt * 16 + g * 4) = pkd;
    }
  }
}

// ---------------- launch ----------------
extern "C" void kernel_launch(void* const* d_in, const int* in_sizes, int n_in,
                              void* d_out, int out_size, void* d_ws, size_t ws_size,
                              hipStream_t stream) {
  const float* x    = (const float*)d_in[0];
  const float* cosf = (const float*)d_in[1];
  const float* sinf = (const float*)d_in[2];
  const float* wq   = (const float*)d_in[3];
  const float* wk   = (const float*)d_in[4];
  const float* wv   = (const float*)d_in[5];
  const float* wo   = (const float*)d_in[6];

  unsigned short* xb   = (unsigned short*)d_ws;      // 8192x2048
  unsigned short* qkvw = xb   + 16777216;            // 3072x2048 (wq|wk|wv)
  unsigned short* wob  = qkvw + 6291456;             // 2048x2048
  unsigned short* qkv  = wob  + 4194304;             // 8192x3072 (Q|K|Vrow)
  unsigned short* Vtg  = qkv  + 25165824;            // 512x8192 (V^T)
  unsigned short* AO   = Vtg  + 4194304;             // 8192x2048

  // one-time: allow 128 KB dynamic LDS for the gemm kernels (host-side attr)
  static int _attr_once = []() {
    hipFuncSetAttribute((const void*)gemm_bt<0>, hipFuncAttributeMaxDynamicSharedMemorySize, 131072);
    hipFuncSetAttribute((const void*)gemm_bt<1>, hipFuncAttributeMaxDynamicSharedMemorySize, 131072);
    return 0;
  }();
  (void)_attr_once;

  // fused cast of all 5 inputs: 6815744 float4s, one launch
  cvt_all<<<26624, 256, 0, stream>>>(x, wq, wk, wv, wo, xb, qkvw, wob);

  // fused QKV projection + RoPE (Q scale folds log2e): 256^2 tiles (32x12)
  gemm_bt<1><<<384, 512, 131072, stream>>>(xb, qkvw, qkv, Vtg, cosf, sinf, 8192, 3072, 2048, 12);

  attn_fwd<<<1024, 256, 0, stream>>>(qkv, Vtg, AO);

  // output projection: [8192,2048] x [2048,2048]^T, 256^2 tiles (32x8)
  gemm_bt<0><<<256, 512, 131072, stream>>>(AO, wob, d_out, nullptr, nullptr, nullptr, 8192, 2048, 2048, 8);
}

// Round 18
// 342.426 us; speedup vs baseline: 1.0523x; 1.0523x over previous
//
#include <hip/hip_runtime.h>
#include <hip/hip_bf16.h>
#include <math.h>

typedef __attribute__((ext_vector_type(8))) short short8;
typedef __attribute__((ext_vector_type(4))) float floatx4;

__device__ __forceinline__ float bf2f(unsigned short u) {
  union { unsigned int i; float f; } x; x.i = ((unsigned int)u) << 16; return x.f;
}
__device__ __forceinline__ unsigned short f2bf(float f) {
  union { float f; unsigned int i; } x; x.f = f;
  unsigned int r = x.i + 0x7FFFu + ((x.i >> 16) & 1u);
  return (unsigned short)(r >> 16);
}
__device__ __forceinline__ unsigned int pack2bf(float a, float b) {
  return (unsigned int)f2bf(a) | ((unsigned int)f2bf(b) << 16);
}
__device__ __forceinline__ void gl16(const void* g, void* l) {
  __builtin_amdgcn_global_load_lds(
      (const __attribute__((address_space(1))) unsigned int*)g,
      (__attribute__((address_space(3))) unsigned int*)l, 16, 0, 0);
}

// ---------------- fused fp32 -> bf16 cast (all 5 tensors, one launch) ----------------
__global__ void cvt_all(const float* __restrict__ x,  const float* __restrict__ wq,
                        const float* __restrict__ wk, const float* __restrict__ wv,
                        const float* __restrict__ wo,
                        unsigned short* __restrict__ xb,
                        unsigned short* __restrict__ qkvw,
                        unsigned short* __restrict__ wob) {
  int i = blockIdx.x * blockDim.x + threadIdx.x;     // float4 index, < 6815744
  const float* src; unsigned short* dst; int off;
  if (i < 4194304)      { src = x;  dst = xb;             off = i; }
  else if (i < 5242880) { src = wq; dst = qkvw;           off = i - 4194304; }
  else if (i < 5505024) { src = wk; dst = qkvw + 4194304; off = i - 5242880; }
  else if (i < 5767168) { src = wv; dst = qkvw + 5242880; off = i - 5505024; }
  else                  { src = wo; dst = wob;            off = i - 5767168; }
  float4 v = ((const float4*)src)[off];
  ushort4 o;
  o.x = f2bf(v.x); o.y = f2bf(v.y); o.z = f2bf(v.z); o.w = f2bf(v.w);
  ((ushort4*)dst)[off] = o;
}

// ---------------- GEMM: C = A(MxK) * Bw(NxK)^T (r11/r15/r16-verified, verbatim) ----------------
// v5 K-loop: 256x256 tile, BK=64, 8 waves (2Mx4N), 128 KB dynamic LDS,
// in-wave software pipeline, one barrier + one counted drain per K-tile.
// MODE 1: fused QKV + bitwise-identical RoPE in Q/K epilogue; V transposed.
// MODE 0: f32 row-major out (ld=N).
template<int MODE>
__global__ __launch_bounds__(512, 2) void gemm_bt(const unsigned short* __restrict__ A,
                                                  const unsigned short* __restrict__ Bw,
                                                  void* __restrict__ out0,
                                                  unsigned short* __restrict__ vtg,
                                                  const float* __restrict__ cosf,
                                                  const float* __restrict__ sinf,
                                                  int M, int N, int K, int nbx) {
  extern __shared__ unsigned short SM[];   // 128 KB
  const int nb = gridDim.x;
  const int bid = blockIdx.x;
  const int tile = (bid & 7) * (nb >> 3) + (bid >> 3);   // 8 XCDs, nb % 8 == 0
  const int n0 = (tile % nbx) * 256, m0 = (tile / nbx) * 256;
  const int tid = threadIdx.x;
  const int lane = tid & 63, wave = tid >> 6;
  const int wm = wave >> 2, wn = wave & 3;               // 2M x 4N wave grid
  const int r = lane & 15, g = lane >> 4;
  const int rh = r >> 1;
  const int slot = (((r & 1) << 2) | g) ^ rh;            // read-side granule slot

  const int sg8 = (tid & 7) ^ ((tid >> 3) & 7);
  const int srow = 2 * (tid >> 3) + (sg8 >> 2);
  const int scol = (sg8 & 3) * 8;
  const unsigned short* Agb = A  + (size_t)(m0 + srow) * K + scol;
  const unsigned short* Bgb = Bw + (size_t)(n0 + srow) * K + scol;
  const size_t K128 = (size_t)K * 128;
  char* const SMb = (char*)SM;

  const int aob = (wm * 64 + rh) * 64 + slot * 8;         // + kh*8192 + i*512
  const int bob = 16384 + (wn * 32 + rh) * 64 + slot * 8; // + kh*8192 + j*512

  auto STA = [&](int s, int t, int kh) {
    const unsigned short* gp = Agb + ((size_t)t << 6) + kh * 32;
    char* d = SMb + s * 65536 + kh * 16384 + wave * 1024;
    gl16(gp,        d);
    gl16(gp + K128, d + 8192);
  };
  auto STB = [&](int s, int t, int kh) {
    const unsigned short* gp = Bgb + ((size_t)t << 6) + kh * 32;
    char* d = SMb + s * 65536 + 32768 + kh * 16384 + wave * 1024;
    gl16(gp,        d);
    gl16(gp + K128, d + 8192);
  };

  floatx4 acc[8][4] = {};
  const int NT = K >> 6;

  STA(0, 0, 0); STB(0, 0, 0);
  STA(0, 0, 1); STB(0, 0, 1);
  asm volatile("s_waitcnt vmcnt(0)" ::: "memory");
  __builtin_amdgcn_s_barrier();
  asm volatile("" ::: "memory");

  short8 bfrA[4], afA[4];
#pragma unroll
  for (int j = 0; j < 4; ++j) bfrA[j] = *(const short8*)&SM[bob + j * 512];
#pragma unroll
  for (int i = 0; i < 4; ++i) afA[i] = *(const short8*)&SM[aob + i * 512];

  for (int t = 0; t < NT; ++t) {
    const int s = t & 1;
    const unsigned short* Ls = SM + s * 32768;         // ushort units
    const unsigned short* Ln = SM + (s ^ 1) * 32768;
    const bool pf = (t + 1 < NT);
    short8 afB[4], bfrB[4], afA2[4], afB2[4];

    // ---- q0: MFMA(kh0, i0-3); read kh0 i4-7; stage t+1 kh0 ----
#pragma unroll
    for (int i = 0; i < 4; ++i) afB[i] = *(const short8*)&Ls[aob + (4 + i) * 512];
    if (pf) { STA(s ^ 1, t + 1, 0); STB(s ^ 1, t + 1, 0); }
    __builtin_amdgcn_s_setprio(1);
#pragma unroll
    for (int i = 0; i < 4; ++i)
#pragma unroll
      for (int j = 0; j < 4; ++j)
        acc[i][j] = __builtin_amdgcn_mfma_f32_16x16x32_bf16(afA[i], bfrA[j], acc[i][j], 0, 0, 0);
    __builtin_amdgcn_s_setprio(0);

    // ---- q1: MFMA(kh0, i4-7); read kh1 B + kh1 i0-3; stage t+1 kh1 ----
#pragma unroll
    for (int j = 0; j < 4; ++j) bfrB[j] = *(const short8*)&Ls[bob + 8192 + j * 512];
#pragma unroll
    for (int i = 0; i < 4; ++i) afA2[i] = *(const short8*)&Ls[aob + 8192 + i * 512];
    if (pf) { STA(s ^ 1, t + 1, 1); STB(s ^ 1, t + 1, 1); }
    __builtin_amdgcn_s_setprio(1);
#pragma unroll
    for (int i = 0; i < 4; ++i)
#pragma unroll
      for (int j = 0; j < 4; ++j)
        acc[4 + i][j] = __builtin_amdgcn_mfma_f32_16x16x32_bf16(afB[i], bfrA[j], acc[4 + i][j], 0, 0, 0);
    __builtin_amdgcn_s_setprio(0);

    // ---- q2: MFMA(kh1, i0-3); read kh1 i4-7 ----
#pragma unroll
    for (int i = 0; i < 4; ++i) afB2[i] = *(const short8*)&Ls[aob + 8192 + (4 + i) * 512];
    __builtin_amdgcn_s_setprio(1);
#pragma unroll
    for (int i = 0; i < 4; ++i)
#pragma unroll
      for (int j = 0; j < 4; ++j)
        acc[i][j] = __builtin_amdgcn_mfma_f32_16x16x32_bf16(afA2[i], bfrB[j], acc[i][j], 0, 0, 0);
    __builtin_amdgcn_s_setprio(0);

    // ---- q3: drain reads (WAR) + confirm stages (RAW); barrier; read-ahead ----
    asm volatile("s_waitcnt lgkmcnt(0)" ::: "memory");
    if (pf) asm volatile("s_waitcnt vmcnt(0)" ::: "memory");
    __builtin_amdgcn_s_barrier();
    asm volatile("" ::: "memory");
    if (pf) {
#pragma unroll
      for (int j = 0; j < 4; ++j) bfrA[j] = *(const short8*)&Ln[bob + j * 512];
#pragma unroll
      for (int i = 0; i < 4; ++i) afA[i] = *(const short8*)&Ln[aob + i * 512];
    }
    __builtin_amdgcn_s_setprio(1);
#pragma unroll
    for (int i = 0; i < 4; ++i)
#pragma unroll
      for (int j = 0; j < 4; ++j)
        acc[4 + i][j] = __builtin_amdgcn_mfma_f32_16x16x32_bf16(afB2[i], bfrB[j], acc[4 + i][j], 0, 0, 0);
    __builtin_amdgcn_s_setprio(0);
  }

  // ---- LDS-bounce epilogues ----
  if (MODE == 0) {
    float* SMf = (float*)SM;                 // slab: 256 rows x 64 f32 = 64 KB
    float* outp = (float*)out0;
#pragma unroll
    for (int sp = 0; sp < 4; ++sp) {
      __syncthreads();
      if (wn == sp) {
#pragma unroll
        for (int i = 0; i < 8; ++i)
#pragma unroll
          for (int j = 0; j < 4; ++j)
#pragma unroll
            for (int q = 0; q < 4; ++q)
              SMf[(wm * 128 + i * 16 + g * 4 + q) * 64 + j * 16 + r] = acc[i][j][q];
      }
      __syncthreads();
#pragma unroll
      for (int it = 0; it < 8; ++it) {
        int c = it * 512 + tid;
        int ml = c >> 4, c4 = c & 15;
        float4 v = *(float4*)&SMf[ml * 64 + c4 * 4];
        *(float4*)(outp + (size_t)(m0 + ml) * N + n0 + sp * 64 + c4 * 4) = v;
      }
    }
  } else if (n0 < 2560) {                    // Q/K region: bf16 row-major + fused RoPE
    unsigned short* outp = (unsigned short*)out0;
    const float scale = (n0 < 2048) ? 0.08838834764831845f : 1.0f;  // Q: fold 1/sqrt(128)
#pragma unroll
    for (int sp = 0; sp < 2; ++sp) {
      __syncthreads();
      if (wm == sp) {
#pragma unroll
        for (int i = 0; i < 8; ++i)
#pragma unroll
          for (int j = 0; j < 4; ++j)
#pragma unroll
            for (int q = 0; q < 4; ++q)
              SM[(i * 16 + g * 4 + q) * 256 + wn * 64 + j * 16 + r] = f2bf(acc[i][j][q]);
      }
      __syncthreads();
#pragma unroll
      for (int it = 0; it < 8; ++it) {
        int c = it * 512 + tid;
        int ml = c >> 5, c8 = c & 31;
        union { short8 s; unsigned short u[8]; } v;
        v.s = *(short8*)&SM[ml * 256 + c8 * 8];
        const int row = m0 + sp * 128 + ml;            // global token row
        const int tpos = row & 2047;
        const int d8 = ((n0 + c8 * 8) & 127) >> 3;     // pair-quad index within head
        float4 cc = *(const float4*)(cosf + (size_t)tpos * 64 + d8 * 4);
        float4 ss = *(const float4*)(sinf + (size_t)tpos * 64 + d8 * 4);
        float cv[4] = {cc.x, cc.y, cc.z, cc.w};
        float sv[4] = {ss.x, ss.y, ss.z, ss.w};
#pragma unroll
        for (int jj = 0; jj < 4; ++jj) {
          float tr = bf2f(v.u[2 * jj]);
          float ti = bf2f(v.u[2 * jj + 1]);
          float orr = (tr * cv[jj] - ti * sv[jj]) * scale;
          float oi  = (tr * sv[jj] + ti * cv[jj]) * scale;
          v.u[2 * jj]     = f2bf(orr);
          v.u[2 * jj + 1] = f2bf(oi);
        }
        *(short8*)(outp + (size_t)row * N + n0 + c8 * 8) = v.s;
      }
    }
  } else {                                   // V region: bf16 transposed, ld=8192 (no RoPE)
#pragma unroll
    for (int sp = 0; sp < 8; ++sp) {
      __syncthreads();
      if (wave == sp) {
#pragma unroll
        for (int i = 0; i < 8; ++i)
#pragma unroll
          for (int j = 0; j < 4; ++j)
#pragma unroll
            for (int q = 0; q < 4; ++q) {
              int ml = i * 16 + g * 4 + q;            // 0..127 (wave's m range)
              int nl = j * 16 + r;                    // 0..63  (wave's n range)
              SM[nl * 128 + (((ml >> 3) ^ (nl & 7)) << 3) + (ml & 7)] = f2bf(acc[i][j][q]);
            }
      }
      __syncthreads();
#pragma unroll
      for (int it = 0; it < 2; ++it) {
        int c = it * 512 + tid;
        int nl = c >> 4, m8 = c & 15;
        short8 v = *(short8*)&SM[nl * 128 + ((m8 ^ (nl & 7)) << 3)];
        *(short8*)(vtg + (size_t)(n0 - 2560 + (sp & 3) * 64 + nl) * 8192 + m0 + (sp >> 2) * 128 + m8 * 8) = v;
      }
    }
  }
}

// ---------------- causal GQA flash attention (r7/r11/r16-verified, verbatim) ----------------
__global__ __launch_bounds__(256, 2) void attn_fwd(const unsigned short* __restrict__ QKV,
                                                   const unsigned short* __restrict__ VT,
                                                   unsigned short* __restrict__ O) {
  constexpr int T = 2048;
  constexpr int LDQ = 3072;
  constexpr float NEG = -1e30f;
  __shared__ unsigned short Ks[2][64 * 128];
  __shared__ unsigned short Vs[2][128 * 64];
  const int gid = blockIdx.x;
  const int hb  = gid & 63;                // h + 16*b
  const int qb  = 15 - (gid >> 6);         // 15..0 -- biggest q-block first
  const int h = hb & 15, b = hb >> 4;
  const int kvh = h >> 2;
  const int tid = threadIdx.x, lane = tid & 63, w = tid >> 6;
  const int r = lane & 15, g = lane >> 4;
  const int rbase = (r & 3) + ((r >> 2) << 3);
  const int swzr  = (r & 3) | (((r >> 2) & 1) << 2);
  const size_t bT = (size_t)b * T;

  const unsigned short* Kgb = QKV + bT * LDQ + 2048 + kvh * 128;
  const unsigned short* Vgb = VT + (size_t)(kvh * 128) * 8192 + b * 2048;

  auto STAGE = [&](int bi, int kv0) {
#pragma unroll
    for (int t2 = 0; t2 < 4; ++t2) {
      int ck = w * 4 + t2;
      { int row = ck * 4 + (lane >> 4); int c16 = lane & 15;
        int swz = (row & 3) | (((row >> 3) & 1) << 2);
        gl16(Kgb + (size_t)(kv0 + row) * LDQ + ((c16 ^ swz) << 3),
             (char*)(&Ks[bi][0]) + ck * 1024); }
      { int row = ck * 8 + (lane >> 3); int c16 = lane & 7;
        gl16(Vgb + (size_t)row * 8192 + kv0 + ((c16 ^ (row & 7)) << 3),
             (char*)(&Vs[bi][0]) + ck * 1024); }
    }
  };

  const int q0 = qb * 128;

  short8 qf[2][4];
#pragma unroll
  for (int qt = 0; qt < 2; ++qt) {
    const unsigned short* qp = QKV + (bT + q0 + w * 32 + qt * 16 + r) * LDQ + h * 128;
#pragma unroll
    for (int c = 0; c < 4; ++c) qf[qt][c] = *(const short8*)(qp + c * 32 + g * 8);
  }

  floatx4 acc[8][2] = {};
  float mrun[2] = {NEG, NEG};
  float lrun[2] = {0.f, 0.f};

  const int ntiles = (q0 + 128) >> 6;
  STAGE(0, 0);
  asm volatile("s_waitcnt vmcnt(0)" ::: "memory");
  __syncthreads();

  for (int t = 0; t < ntiles; ++t) {
    const int cur = t & 1;
    const int kv0 = t << 6;
    if (t + 1 < ntiles) STAGE(cur ^ 1, (t + 1) << 6);

    if (kv0 <= q0 + w * 32 + 31) {
      floatx4 st[2][4] = {};
      __builtin_amdgcn_s_setprio(1);
#pragma unroll
      for (int c = 0; c < 4; ++c) {
        short8 kf[4];
#pragma unroll
        for (int kt = 0; kt < 4; ++kt) {
          const int row = rbase + ((kt & 1) << 2) + ((kt >> 1) << 5);
          kf[kt] = *(const short8*)&Ks[cur][row * 128 + (((g + 4 * c) ^ swzr) << 3)];
        }
#pragma unroll
        for (int qt = 0; qt < 2; ++qt)
#pragma unroll
          for (int kt = 0; kt < 4; ++kt)
            st[qt][kt] = __builtin_amdgcn_mfma_f32_16x16x32_bf16(kf[kt], qf[qt][c], st[qt][kt], 0, 0, 0);
      }
      __builtin_amdgcn_s_setprio(0);

      short8 va[2][8];
#pragma unroll
      for (int kc = 0; kc < 2; ++kc)
#pragma unroll
        for (int dt = 0; dt < 8; ++dt)
          va[kc][dt] = *(const short8*)&Vs[cur][(dt * 16 + r) * 64 + (((g + 4 * kc) ^ (r & 7)) << 3)];

#pragma unroll
      for (int qt = 0; qt < 2; ++qt) {
        const int qmin = q0 + w * 32 + qt * 16;
        const int qrow = qmin + r;
        float x[4][4];
        bool needmask = (kv0 + 64 > qmin);
#pragma unroll
        for (int kt = 0; kt < 4; ++kt) {
          const int kvb = kv0 + ((kt >> 1) << 5) + (g << 3) + ((kt & 1) << 2);
#pragma unroll
          for (int j = 0; j < 4; ++j) {
            float v = st[qt][kt][j];
            if (needmask) v = (kvb + j <= qrow) ? v : NEG;
            x[kt][j] = v;
          }
        }
        float mloc = x[0][0];
#pragma unroll
        for (int kt = 0; kt < 4; ++kt)
#pragma unroll
          for (int j = 0; j < 4; ++j) mloc = fmaxf(mloc, x[kt][j]);
        mloc = fmaxf(mloc, __shfl_xor(mloc, 16));
        mloc = fmaxf(mloc, __shfl_xor(mloc, 32));
        if (!__all(mloc <= mrun[qt] + 8.f)) {    // defer-max (T13)
          float mnew = fmaxf(mrun[qt], mloc);
          float al = __expf(mrun[qt] - mnew);
          mrun[qt] = mnew;
          lrun[qt] *= al;
#pragma unroll
          for (int dt = 0; dt < 8; ++dt) acc[dt][qt] *= al;
        }
        float pr[4][4], ssum = 0.f;
#pragma unroll
        for (int kt = 0; kt < 4; ++kt)
#pragma unroll
          for (int j = 0; j < 4; ++j) { pr[kt][j] = __expf(x[kt][j] - mrun[qt]); ssum += pr[kt][j]; }
        ssum += __shfl_xor(ssum, 16);
        ssum += __shfl_xor(ssum, 32);
        lrun[qt] += ssum;
        uint2 pk[4];
#pragma unroll
        for (int kt = 0; kt < 4; ++kt) {
          pk[kt].x = pack2bf(pr[kt][0], pr[kt][1]);
          pk[kt].y = pack2bf(pr[kt][2], pr[kt][3]);
        }
        __builtin_amdgcn_s_setprio(1);
#pragma unroll
        for (int kc = 0; kc < 2; ++kc) {
          union { unsigned int u[4]; short8 s; } bw;
          bw.u[0] = pk[2 * kc].x;
          bw.u[1] = pk[2 * kc].y;
          bw.u[2] = pk[2 * kc + 1].x;
          bw.u[3] = pk[2 * kc + 1].y;
#pragma unroll
          for (int dt = 0; dt < 8; ++dt)
            acc[dt][qt] = __builtin_amdgcn_mfma_f32_16x16x32_bf16(va[kc][dt], bw.s, acc[dt][qt], 0, 0, 0);
        }
        __builtin_amdgcn_s_setprio(0);
      }
    }

    asm volatile("s_waitcnt vmcnt(0)" ::: "memory");
    __syncthreads();
  }

  // ---- epilogue: O[q][d] = acc^T / l ----
#pragma unroll
  for (int qt = 0; qt < 2; ++qt) {
    float inv = 1.f / lrun[qt];
    unsigned short* op = O + (bT + q0 + w * 32 + qt * 16 + r) * 2048 + h * 128;
#pragma unroll
    for (int dt = 0; dt < 8; ++dt) {
      uint2 pkd;
      pkd.x = pack2bf(acc[dt][qt][0] * inv, acc[dt][qt][1] * inv);
      pkd.y = pack2bf(acc[dt][qt][2] * inv, acc[dt][qt][3] * inv);
      *(uint2*)(op + dt * 16 + g * 4) = pkd;
    }
  }
}

// ---------------- launch ----------------
extern "C" void kernel_launch(void* const* d_in, const int* in_sizes, int n_in,
                              void* d_out, int out_size, void* d_ws, size_t ws_size,
                              hipStream_t stream) {
  const float* x    = (const float*)d_in[0];
  const float* cosf = (const float*)d_in[1];
  const float* sinf = (const float*)d_in[2];
  const float* wq   = (const float*)d_in[3];
  const float* wk   = (const float*)d_in[4];
  const float* wv   = (const float*)d_in[5];
  const float* wo   = (const float*)d_in[6];

  unsigned short* xb   = (unsigned short*)d_ws;      // 8192x2048
  unsigned short* qkvw = xb   + 16777216;            // 3072x2048 (wq|wk|wv)
  unsigned short* wob  = qkvw + 6291456;             // 2048x2048
  unsigned short* qkv  = wob  + 4194304;             // 8192x3072 (Q|K|Vrow)
  unsigned short* Vtg  = qkv  + 25165824;            // 512x8192 (V^T)
  unsigned short* AO   = Vtg  + 4194304;             // 8192x2048

  // one-time: allow 128 KB dynamic LDS for the gemm kernels (host-side attr)
  static int _attr_once = []() {
    hipFuncSetAttribute((const void*)gemm_bt<0>, hipFuncAttributeMaxDynamicSharedMemorySize, 131072);
    hipFuncSetAttribute((const void*)gemm_bt<1>, hipFuncAttributeMaxDynamicSharedMemorySize, 131072);
    return 0;
  }();
  (void)_attr_once;

  // fused cast of all 5 inputs: 6815744 float4s, one launch
  cvt_all<<<26624, 256, 0, stream>>>(x, wq, wk, wv, wo, xb, qkvw, wob);

  // fused QKV projection + RoPE: [8192,2048] x [3072,2048]^T, 256^2 tiles (32x12)
  gemm_bt<1><<<384, 512, 131072, stream>>>(xb, qkvw, qkv, Vtg, cosf, sinf, 8192, 3072, 2048, 12);

  attn_fwd<<<1024, 256, 0, stream>>>(qkv, Vtg, AO);

  // output projection: [8192,2048] x [2048,2048]^T, 256^2 tiles (32x8)
  gemm_bt<0><<<256, 512, 131072, stream>>>(AO, wob, d_out, nullptr, nullptr, nullptr, 8192, 2048, 2048, 8);
}